// Round 6
// baseline (219.566 us; speedup 1.0000x reference)
//
#include <hip/hip_runtime.h>
#include <math.h>

#define BATCH 64
#define TT 128
#define VV 32
#define DD 128
#define OO 512
#define N3 384
#define NN 768

// workspace layout (float offsets)
#define OFF_X      0u          // 1,048,576  x[B,T,D]
#define OFF_XPC    1048576u    // 6,291,456  xp combined [B*T, 768] (a:0..383, b:384..767)
#define OFF_GSEQ   7340032u    // 1,048,576  GRU-A outputs
#define OFF_HSEQ   8388608u    // 1,048,576  GRU-B outputs
#define OFF_INTS   9437184u    // mask[8192], ridx[8192], lengths[64] as int32
#define OFF_ALPHA  9453632u    // 8,192
#define OFF_CPART  9461824u    // 65,536 partial c
// total ≈ 9,527,360 floats ≈ 38.1 MB

// K1: x[b,t,:] = sum_v emb[codes[b,t,v]]; mask[b,t] = (sum_d x != 0)
__global__ __launch_bounds__(128) void k_gather(const int* __restrict__ codes,
        const float* __restrict__ emb, float* __restrict__ x, int* __restrict__ mask) {
    int bt = blockIdx.x;
    int d = threadIdx.x;
    const int* cp = codes + (size_t)bt * VV;
    float acc = 0.f;
    #pragma unroll 8
    for (int v = 0; v < VV; ++v) {
        int code = cp[v];                 // wave-uniform
        acc += emb[(size_t)code * DD + d];
    }
    x[(size_t)bt * DD + d] = acc;
    float s = acc;
    #pragma unroll
    for (int off = 32; off; off >>= 1) s += __shfl_xor(s, off);
    __shared__ float red[2];
    if ((d & 63) == 0) red[d >> 6] = s;
    __syncthreads();
    if (d == 0) mask[bt] = ((red[0] + red[1]) != 0.0f) ? 1 : 0;
}

// K2: lengths[b] = popcount(mask row); ridx[b,t] = len-1-t (may be negative)
__global__ __launch_bounds__(128) void k_len(const int* __restrict__ mask,
        int* __restrict__ lengths, int* __restrict__ ridx) {
    int b = blockIdx.x, t = threadIdx.x;
    int m = mask[b * TT + t];
    unsigned long long bal = __ballot(m != 0);
    __shared__ int cnt[2];
    if ((t & 63) == 0) cnt[t >> 6] = __popcll(bal);
    __syncthreads();
    int len = cnt[0] + cnt[1];
    if (t == 0) lengths[b] = len;
    ridx[b * TT + t] = len - 1 - t;
}

// K3: xpc = x @ [a_kernel | b_kernel] + [bi_a | bi_b]   (M=8192,K=128,N=768)
__global__ __launch_bounds__(256) void k_xp(const float* __restrict__ x,
        const float* __restrict__ akern, const float* __restrict__ bkern,
        const float* __restrict__ abias, const float* __restrict__ bbias,
        float* __restrict__ xpc) {
    __shared__ __attribute__((aligned(16))) float As[32][68];  // As[k][m] transposed
    __shared__ __attribute__((aligned(16))) float Bs[32][68];
    int mb = blockIdx.x, nb = blockIdx.y;
    int n0 = nb * 64;
    int tid = threadIdx.x;
    int tx = tid & 15, ty = tid >> 4;
    float acc[4][4] = {};
    for (int k0 = 0; k0 < DD; k0 += 32) {
        #pragma unroll
        for (int i = 0; i < 2; ++i) {
            int s = tid * 2 + i;
            int row = s >> 3, kk = (s & 7) * 4;
            float4 v = *reinterpret_cast<const float4*>(x + (size_t)(mb * 64 + row) * DD + k0 + kk);
            As[kk][row] = v.x; As[kk+1][row] = v.y; As[kk+2][row] = v.z; As[kk+3][row] = v.w;
        }
        #pragma unroll
        for (int i = 0; i < 2; ++i) {
            int s = tid * 2 + i;
            int kk = s >> 4, c = (s & 15) * 4;
            int n = n0 + c;
            const float* src = (n < N3) ? (akern + (size_t)(k0 + kk) * N3 + n)
                                        : (bkern + (size_t)(k0 + kk) * N3 + (n - N3));
            *reinterpret_cast<float4*>(&Bs[kk][c]) = *reinterpret_cast<const float4*>(src);
        }
        __syncthreads();
        #pragma unroll
        for (int kk = 0; kk < 32; ++kk) {
            float4 a = *reinterpret_cast<const float4*>(&As[kk][ty * 4]);
            float4 bv = *reinterpret_cast<const float4*>(&Bs[kk][tx * 4]);
            float av[4] = {a.x, a.y, a.z, a.w};
            float bw[4] = {bv.x, bv.y, bv.z, bv.w};
            #pragma unroll
            for (int i2 = 0; i2 < 4; ++i2)
                #pragma unroll
                for (int j2 = 0; j2 < 4; ++j2)
                    acc[i2][j2] = fmaf(av[i2], bw[j2], acc[i2][j2]);
        }
        __syncthreads();
    }
    int nbase = n0 + tx * 4;
    float4 bias;
    if (nbase < N3) bias = *reinterpret_cast<const float4*>(abias + nbase);
    else            bias = *reinterpret_cast<const float4*>(bbias + (nbase - N3));
    #pragma unroll
    for (int i2 = 0; i2 < 4; ++i2) {
        int m = mb * 64 + ty * 4 + i2;
        float4 o;
        o.x = acc[i2][0] + bias.x; o.y = acc[i2][1] + bias.y;
        o.z = acc[i2][2] + bias.z; o.w = acc[i2][3] + bias.w;
        *reinterpret_cast<float4*>(xpc + (size_t)m * NN + nbase) = o;
    }
}

__device__ __forceinline__ float fast_sigmoid(float x) {
    return 1.f / (1.f + __expf(-x));
}
__device__ __forceinline__ float fast_tanh(float x) {
    float xc = fminf(fmaxf(x, -15.f), 15.f);
    float e2 = __expf(2.f * xc);
    return (e2 - 1.f) / (e2 + 1.f);
}

// K4: sequential GRU, TWO batches per block (same gru => same rec matrix, so
// the per-step weight stream from L2 — the measured floor of rounds 1-5 at
// ~196KB/step/CU — is amortized over 2 dot products, and 64 blocks (8/XCD)
// double the per-CU L2 share. 768 threads: thread t owns output j = t mod 384
// and k-half [64*(t>=384), +64) = 64 weight floats (asm-pinned; resident if
// the allocator cooperates, streamed-but-halved if not).
#define LOADW(i) \
    float w##i##_x, w##i##_y, w##i##_z, w##i##_w; \
    { const float* rp = rec + (size_t)(k0 + 4 * i) * N3 + j; \
      w##i##_x = rp[0]; w##i##_y = rp[N3]; w##i##_z = rp[2 * N3]; w##i##_w = rp[3 * N3]; } \
    asm volatile("" : "+v"(w##i##_x), "+v"(w##i##_y), "+v"(w##i##_z), "+v"(w##i##_w));
#define DOTW2(i) { \
    float4 hv0 = *reinterpret_cast<const float4*>(&h_lds2[0][k0 + 4 * i]); \
    float4 hv1 = *reinterpret_cast<const float4*>(&h_lds2[1][k0 + 4 * i]); \
    a0 = fmaf(hv0.x, w##i##_x, a0); a1 = fmaf(hv0.y, w##i##_y, a1); \
    a2 = fmaf(hv0.z, w##i##_z, a2); a3 = fmaf(hv0.w, w##i##_w, a3); \
    e0 = fmaf(hv1.x, w##i##_x, e0); e1 = fmaf(hv1.y, w##i##_y, e1); \
    e2 = fmaf(hv1.z, w##i##_z, e2); e3 = fmaf(hv1.w, w##i##_w, e3); }

__global__ __launch_bounds__(768, 3)
void k_gru(
        const float* __restrict__ arec, const float* __restrict__ abias,
        const float* __restrict__ brec, const float* __restrict__ bbias,
        const float* __restrict__ xpc, const int* __restrict__ mask,
        const int* __restrict__ ridx, float* __restrict__ gseq, float* __restrict__ hseq) {
    int pair = blockIdx.x & 31;            // 32 batch pairs
    int gru = blockIdx.x >> 5;
    int b0 = pair * 2, b1 = pair * 2 + 1;
    const float* rec  = gru ? brec : arec;
    const float* bias = gru ? bbias : abias;
    float* seq = gru ? hseq : gseq;
    int t = threadIdx.x;
    int half = (t >= N3) ? 1 : 0;          // wave-uniform (384 = 6 waves)
    int j = t - half * N3;                 // output column 0..383
    int k0 = half * 64;                    // k-range start
    LOADW(0)  LOADW(1)  LOADW(2)  LOADW(3)
    LOADW(4)  LOADW(5)  LOADW(6)  LOADW(7)
    LOADW(8)  LOADW(9)  LOADW(10) LOADW(11)
    LOADW(12) LOADW(13) LOADW(14) LOADW(15)
    __shared__ __attribute__((aligned(16))) float h_lds2[2][DD];
    __shared__ float part2[2][768];
    __shared__ int smask2[2][TT];
    __shared__ int sridx2[2][TT];
    if (t < TT)          { smask2[0][t] = mask[b0 * TT + t]; sridx2[0][t] = ridx[b0 * TT + t]; }
    else if (t < 2 * TT) { int u = t - TT;
                           smask2[1][u] = mask[b1 * TT + u]; sridx2[1][u] = ridx[b1 * TT + u]; }
    if (t < 2 * DD) h_lds2[t >> 7][t & 127] = 0.f;
    // gate-thread constants (t < 256): bi = t>>7, d = t&127 (same gru biases)
    float bz_r = 0.f, br_r = 0.f, bh_r = 0.f;
    if (t < 2 * DD) {
        int d = t & 127;
        bz_r = bias[N3 + d];  br_r = bias[N3 + DD + d];  bh_r = bias[N3 + 2 * DD + d];
    }
    float hreg = 0.f;
    __syncthreads();
    const float* xpb0 = xpc + (size_t)b0 * TT * NN + gru * N3;
    const float* xpb1 = xpc + (size_t)b1 * TT * NN + gru * N3;
    for (int step = 0; step < TT; ++step) {
        int m0 = smask2[0][step], m1 = smask2[1][step];   // uniform
        if (!(m0 | m1)) {                  // both carried: no barriers needed
            if (t < 2 * DD) {
                int bi = t >> 7, d = t & 127;
                seq[(size_t)((bi ? b1 : b0) * TT + step) * DD + d] = hreg;
            }
            continue;
        }
        float xz = 0.f, xr = 0.f, xh = 0.f;
        if (t < 2 * DD) {                  // prefetch input projection (overlaps dot)
            int bi = t >> 7, d = t & 127;
            int mi = bi ? m1 : m0;
            if (mi) {                      // mask=1 <=> ridx>=0
                int row = sridx2[bi][step];
                const float* xrow = (bi ? xpb1 : xpb0) + (size_t)row * NN;
                xz = xrow[d]; xr = xrow[DD + d]; xh = xrow[2 * DD + d];
            }
        }
        float a0 = 0.f, a1 = 0.f, a2 = 0.f, a3 = 0.f;
        float e0 = 0.f, e1 = 0.f, e2 = 0.f, e3 = 0.f;
        DOTW2(0)  DOTW2(1)  DOTW2(2)  DOTW2(3)
        DOTW2(4)  DOTW2(5)  DOTW2(6)  DOTW2(7)
        DOTW2(8)  DOTW2(9)  DOTW2(10) DOTW2(11)
        DOTW2(12) DOTW2(13) DOTW2(14) DOTW2(15)
        part2[0][t] = (a0 + a1) + (a2 + a3);
        part2[1][t] = (e0 + e1) + (e2 + e3);
        __syncthreads();
        if (t < 2 * DD) {
            int bi = t >> 7, d = t & 127;
            int mi = bi ? m1 : m0;
            size_t so = (size_t)((bi ? b1 : b0) * TT + step) * DD + d;
            if (mi) {
                const float* pp = &part2[bi][0];
                float hz = pp[d]          + pp[d + N3]          + bz_r;
                float hr = pp[d + DD]     + pp[d + N3 + DD]     + br_r;
                float hh = pp[d + 2 * DD] + pp[d + N3 + 2 * DD] + bh_r;
                float z = fast_sigmoid(xz + hz);
                float r = fast_sigmoid(xr + hr);
                float hc = fast_tanh(xh + r * hh);
                float hnew = z * hreg + (1.f - z) * hc;
                hreg = hnew;
                h_lds2[bi][d] = hnew;
                seq[so] = hnew;
            } else {
                seq[so] = hreg;            // carry-through for this batch only
            }
        }
        __syncthreads();
    }
}

// K5: alpha = softmax_t(gseq @ alpha_w + alpha_b)
__global__ __launch_bounds__(128) void k_alpha(const float* __restrict__ gseq,
        const float* __restrict__ alpha_w, const float* __restrict__ alpha_b,
        float* __restrict__ alpha) {
    int b = blockIdx.x, t = threadIdx.x;
    __shared__ float aw[DD];
    aw[t] = alpha_w[t];
    __syncthreads();
    const float* g = gseq + (size_t)(b * TT + t) * DD;
    float acc = 0.f;
    #pragma unroll
    for (int k = 0; k < DD; k += 4) {
        float4 gv = *reinterpret_cast<const float4*>(g + k);
        acc = fmaf(gv.x, aw[k],     acc);
        acc = fmaf(gv.y, aw[k + 1], acc);
        acc = fmaf(gv.z, aw[k + 2], acc);
        acc = fmaf(gv.w, aw[k + 3], acc);
    }
    float logit = acc + alpha_b[0];
    float mx = logit;
    #pragma unroll
    for (int off = 32; off; off >>= 1) mx = fmaxf(mx, __shfl_xor(mx, off));
    __shared__ float redm[2];
    if ((t & 63) == 0) redm[t >> 6] = mx;
    __syncthreads();
    mx = fmaxf(redm[0], redm[1]);
    float e = expf(logit - mx);
    float s = e;
    #pragma unroll
    for (int off = 32; off; off >>= 1) s += __shfl_xor(s, off);
    __shared__ float reds[2];
    if ((t & 63) == 0) reds[t >> 6] = s;
    __syncthreads();
    alpha[b * TT + t] = e / (reds[0] + reds[1]);
}

// K6: cpart[(b,grp)] = sum over 16 t's of alpha * tanh(h @ beta_w + beta_b) * x
__global__ __launch_bounds__(128) void k_beta(const float* __restrict__ hseq,
        const float* __restrict__ x, const float* __restrict__ beta_w,
        const float* __restrict__ beta_b, const float* __restrict__ alpha,
        float* __restrict__ cpart) {
    __shared__ __attribute__((aligned(16))) float bw[DD][DD];   // 64 KB
    __shared__ __attribute__((aligned(16))) float hr[4][DD];
    __shared__ float cred[4][DD];
    int b = blockIdx.x >> 3, grp = blockIdx.x & 7;
    int tid = threadIdx.x;
    for (int i = tid; i < DD * DD / 4; i += 128) {
        float4 v = *reinterpret_cast<const float4*>(beta_w + (size_t)i * 4);
        *reinterpret_cast<float4*>(&bw[0][0] + (size_t)i * 4) = v;
    }
    int trow = tid >> 5, dq = (tid & 31) * 4;
    float bb0 = beta_b[dq], bb1 = beta_b[dq + 1], bb2 = beta_b[dq + 2], bb3 = beta_b[dq + 3];
    float c0 = 0.f, c1 = 0.f, c2 = 0.f, c3 = 0.f;
    for (int tg = 0; tg < 4; ++tg) {
        int t = grp * 16 + tg * 4 + trow;
        size_t rowoff = (size_t)(b * TT + t) * DD;
        float4 hv = *reinterpret_cast<const float4*>(hseq + rowoff + dq);
        __syncthreads();                    // protect previous iteration's hr readers
        *reinterpret_cast<float4*>(&hr[trow][dq]) = hv;
        __syncthreads();
        float a0 = 0.f, a1 = 0.f, a2 = 0.f, a3 = 0.f;
        #pragma unroll 8
        for (int k = 0; k < DD; ++k) {
            float hk = hr[trow][k];
            float4 w = *reinterpret_cast<const float4*>(&bw[k][dq]);
            a0 = fmaf(hk, w.x, a0); a1 = fmaf(hk, w.y, a1);
            a2 = fmaf(hk, w.z, a2); a3 = fmaf(hk, w.w, a3);
        }
        float al = alpha[b * TT + t];
        float4 xv = *reinterpret_cast<const float4*>(x + rowoff + dq);
        c0 = fmaf(al * tanhf(a0 + bb0), xv.x, c0);
        c1 = fmaf(al * tanhf(a1 + bb1), xv.y, c1);
        c2 = fmaf(al * tanhf(a2 + bb2), xv.z, c2);
        c3 = fmaf(al * tanhf(a3 + bb3), xv.w, c3);
    }
    cred[trow][dq] = c0; cred[trow][dq + 1] = c1;
    cred[trow][dq + 2] = c2; cred[trow][dq + 3] = c3;
    __syncthreads();
    if (tid < 32) {
        #pragma unroll
        for (int i = 0; i < 4; ++i) {
            int d = tid * 4 + i;
            float sum = cred[0][d] + cred[1][d] + cred[2][d] + cred[3][d];
            cpart[(size_t)(b * 8 + grp) * DD + d] = sum;
        }
    }
}

// K7: out[b] = (sum of 8 cpart slices) @ cls_w + cls_b
__global__ __launch_bounds__(256) void k_out(const float* __restrict__ cpart,
        const float* __restrict__ cls_w, const float* __restrict__ cls_b,
        float* __restrict__ out) {
    __shared__ float cl[DD];
    int b = blockIdx.x, tid = threadIdx.x;
    if (tid < DD) {
        float s = 0.f;
        #pragma unroll
        for (int p = 0; p < 8; ++p) s += cpart[(size_t)(b * 8 + p) * DD + tid];
        cl[tid] = s;
    }
    __syncthreads();
    #pragma unroll
    for (int rep = 0; rep < 2; ++rep) {
        int o = tid + rep * 256;
        float acc = cls_b[o];
        #pragma unroll 8
        for (int k = 0; k < DD; ++k)
            acc = fmaf(cl[k], cls_w[(size_t)k * OO + o], acc);
        out[(size_t)b * OO + o] = acc;
    }
}

extern "C" void kernel_launch(void* const* d_in, const int* in_sizes, int n_in,
                              void* d_out, int out_size, void* d_ws, size_t ws_size,
                              hipStream_t stream) {
    const int*   codes   = (const int*)d_in[0];
    const float* emb     = (const float*)d_in[1];
    const float* akern   = (const float*)d_in[2];
    const float* arec    = (const float*)d_in[3];
    const float* abias   = (const float*)d_in[4];
    const float* bkern   = (const float*)d_in[5];
    const float* brec    = (const float*)d_in[6];
    const float* bbias   = (const float*)d_in[7];
    const float* alpha_w = (const float*)d_in[8];
    const float* alpha_b = (const float*)d_in[9];
    const float* beta_w  = (const float*)d_in[10];
    const float* beta_b  = (const float*)d_in[11];
    const float* cls_w   = (const float*)d_in[12];
    const float* cls_b   = (const float*)d_in[13];
    float* ws   = (float*)d_ws;
    float* x    = ws + OFF_X;
    float* xpc  = ws + OFF_XPC;
    float* gseq = ws + OFF_GSEQ;
    float* hseq = ws + OFF_HSEQ;
    int*   ints = (int*)(ws + OFF_INTS);
    int* mask    = ints;
    int* ridx    = ints + 8192;
    int* lengths = ints + 16384;
    float* alpha = ws + OFF_ALPHA;
    float* cpart = ws + OFF_CPART;
    float* out   = (float*)d_out;

    k_gather<<<BATCH * TT, 128, 0, stream>>>(codes, emb, x, mask);
    k_len<<<BATCH, 128, 0, stream>>>(mask, lengths, ridx);
    dim3 g3(128, 12);
    k_xp<<<g3, 256, 0, stream>>>(x, akern, bkern, abias, bbias, xpc);
    k_gru<<<64, 768, 0, stream>>>(arec, abias, brec, bbias, xpc, mask, ridx, gseq, hseq);
    k_alpha<<<BATCH, 128, 0, stream>>>(gseq, alpha_w, alpha_b, alpha);
    k_beta<<<BATCH * 8, 128, 0, stream>>>(hseq, x, beta_w, beta_b, alpha, cpart);
    k_out<<<BATCH, 256, 0, stream>>>(cpart, cls_w, cls_b, out);
}

// Round 7
// 170.722 us; speedup vs baseline: 1.2861x; 1.2861x over previous
//
#include <hip/hip_runtime.h>
#include <math.h>

#define BATCH 64
#define TT 128
#define VV 32
#define DD 128
#define OO 512
#define N3 384
#define NN 768

// workspace layout (float offsets)
#define OFF_X      0u          // 1,048,576  x[B,T,D]
#define OFF_XPC    1048576u    // 6,291,456  xp combined [B*T, 768] (a:0..383, b:384..767)
#define OFF_GSEQ   7340032u    // 1,048,576  GRU-A outputs
#define OFF_HSEQ   8388608u    // 1,048,576  GRU-B outputs
#define OFF_INTS   9437184u    // mask[8192], ridx[8192], lengths[64] as int32
#define OFF_ALPHA  9453632u    // 8,192
#define OFF_CPART  9461824u    // 65,536 partial c
// total ≈ 9,527,360 floats ≈ 38.1 MB

// K1: x[b,t,:] = sum_v emb[codes[b,t,v]]; mask[b,t] = (sum_d x != 0)
__global__ __launch_bounds__(128) void k_gather(const int* __restrict__ codes,
        const float* __restrict__ emb, float* __restrict__ x, int* __restrict__ mask) {
    int bt = blockIdx.x;
    int d = threadIdx.x;
    const int* cp = codes + (size_t)bt * VV;
    float acc = 0.f;
    #pragma unroll 8
    for (int v = 0; v < VV; ++v) {
        int code = cp[v];                 // wave-uniform
        acc += emb[(size_t)code * DD + d];
    }
    x[(size_t)bt * DD + d] = acc;
    float s = acc;
    #pragma unroll
    for (int off = 32; off; off >>= 1) s += __shfl_xor(s, off);
    __shared__ float red[2];
    if ((d & 63) == 0) red[d >> 6] = s;
    __syncthreads();
    if (d == 0) mask[bt] = ((red[0] + red[1]) != 0.0f) ? 1 : 0;
}

// K2: lengths[b] = popcount(mask row); ridx[b,t] = len-1-t (may be negative)
__global__ __launch_bounds__(128) void k_len(const int* __restrict__ mask,
        int* __restrict__ lengths, int* __restrict__ ridx) {
    int b = blockIdx.x, t = threadIdx.x;
    int m = mask[b * TT + t];
    unsigned long long bal = __ballot(m != 0);
    __shared__ int cnt[2];
    if ((t & 63) == 0) cnt[t >> 6] = __popcll(bal);
    __syncthreads();
    int len = cnt[0] + cnt[1];
    if (t == 0) lengths[b] = len;
    ridx[b * TT + t] = len - 1 - t;
}

// K3: xpc = x @ [a_kernel | b_kernel] + [bi_a | bi_b]   (M=8192,K=128,N=768)
__global__ __launch_bounds__(256) void k_xp(const float* __restrict__ x,
        const float* __restrict__ akern, const float* __restrict__ bkern,
        const float* __restrict__ abias, const float* __restrict__ bbias,
        float* __restrict__ xpc) {
    __shared__ __attribute__((aligned(16))) float As[32][68];  // As[k][m] transposed
    __shared__ __attribute__((aligned(16))) float Bs[32][68];
    int mb = blockIdx.x, nb = blockIdx.y;
    int n0 = nb * 64;
    int tid = threadIdx.x;
    int tx = tid & 15, ty = tid >> 4;
    float acc[4][4] = {};
    for (int k0 = 0; k0 < DD; k0 += 32) {
        #pragma unroll
        for (int i = 0; i < 2; ++i) {
            int s = tid * 2 + i;
            int row = s >> 3, kk = (s & 7) * 4;
            float4 v = *reinterpret_cast<const float4*>(x + (size_t)(mb * 64 + row) * DD + k0 + kk);
            As[kk][row] = v.x; As[kk+1][row] = v.y; As[kk+2][row] = v.z; As[kk+3][row] = v.w;
        }
        #pragma unroll
        for (int i = 0; i < 2; ++i) {
            int s = tid * 2 + i;
            int kk = s >> 4, c = (s & 15) * 4;
            int n = n0 + c;
            const float* src = (n < N3) ? (akern + (size_t)(k0 + kk) * N3 + n)
                                        : (bkern + (size_t)(k0 + kk) * N3 + (n - N3));
            *reinterpret_cast<float4*>(&Bs[kk][c]) = *reinterpret_cast<const float4*>(src);
        }
        __syncthreads();
        #pragma unroll
        for (int kk = 0; kk < 32; ++kk) {
            float4 a = *reinterpret_cast<const float4*>(&As[kk][ty * 4]);
            float4 bv = *reinterpret_cast<const float4*>(&Bs[kk][tx * 4]);
            float av[4] = {a.x, a.y, a.z, a.w};
            float bw[4] = {bv.x, bv.y, bv.z, bv.w};
            #pragma unroll
            for (int i2 = 0; i2 < 4; ++i2)
                #pragma unroll
                for (int j2 = 0; j2 < 4; ++j2)
                    acc[i2][j2] = fmaf(av[i2], bw[j2], acc[i2][j2]);
        }
        __syncthreads();
    }
    int nbase = n0 + tx * 4;
    float4 bias;
    if (nbase < N3) bias = *reinterpret_cast<const float4*>(abias + nbase);
    else            bias = *reinterpret_cast<const float4*>(bbias + (nbase - N3));
    #pragma unroll
    for (int i2 = 0; i2 < 4; ++i2) {
        int m = mb * 64 + ty * 4 + i2;
        float4 o;
        o.x = acc[i2][0] + bias.x; o.y = acc[i2][1] + bias.y;
        o.z = acc[i2][2] + bias.z; o.w = acc[i2][3] + bias.w;
        *reinterpret_cast<float4*>(xpc + (size_t)m * NN + nbase) = o;
    }
}

__device__ __forceinline__ float fast_sigmoid(float x) {
    return 1.f / (1.f + __expf(-x));
}
__device__ __forceinline__ float fast_tanh(float x) {
    float xc = fminf(fmaxf(x, -15.f), 15.f);
    float e2 = __expf(2.f * xc);
    return (e2 - 1.f) / (e2 + 1.f);
}

// K4: sequential GRU v3. 128 blocks = (gru,b); 768 threads (12 waves).
// Thread t: c4 = t%96 (owns 4 consecutive output cols j4=4*c4..+3),
//           kc = t/96 (owns k-rows krow0=kc*16..+15).
// 64 weights/thread as 16 float4 (coalesced loads, asm-pinned; r4/r5 showed
// this footprint stays resident: VGPR 68 = 64+4). Per step: 4 uniform b128
// h-reads + 64 FMA + 1 b128 partial write (vs r5's 16 b128 reads — the
// measured 2140 cyc/step ≈ 240 LDS instrs × 9 cyc; this cuts to ~110 instrs).
#define LOADW(i) \
    float4 w##i = *reinterpret_cast<const float4*>(rec + (size_t)(krow0 + i) * N3 + j4); \
    asm volatile("" : "+v"(w##i.x), "+v"(w##i.y), "+v"(w##i.z), "+v"(w##i.w));
#define DOTQ(q, i0, i1, i2, i3) { \
    float4 hv = *reinterpret_cast<const float4*>(&h_lds[krow0 + 4 * (q)]); \
    acc.x = fmaf(hv.x, w##i0.x, acc.x); acc.y = fmaf(hv.x, w##i0.y, acc.y); \
    acc.z = fmaf(hv.x, w##i0.z, acc.z); acc.w = fmaf(hv.x, w##i0.w, acc.w); \
    acc.x = fmaf(hv.y, w##i1.x, acc.x); acc.y = fmaf(hv.y, w##i1.y, acc.y); \
    acc.z = fmaf(hv.y, w##i1.z, acc.z); acc.w = fmaf(hv.y, w##i1.w, acc.w); \
    acc.x = fmaf(hv.z, w##i2.x, acc.x); acc.y = fmaf(hv.z, w##i2.y, acc.y); \
    acc.z = fmaf(hv.z, w##i2.z, acc.z); acc.w = fmaf(hv.z, w##i2.w, acc.w); \
    acc.x = fmaf(hv.w, w##i3.x, acc.x); acc.y = fmaf(hv.w, w##i3.y, acc.y); \
    acc.z = fmaf(hv.w, w##i3.z, acc.z); acc.w = fmaf(hv.w, w##i3.w, acc.w); }

__global__ __launch_bounds__(768, 3)
void k_gru(
        const float* __restrict__ arec, const float* __restrict__ abias,
        const float* __restrict__ brec, const float* __restrict__ bbias,
        const float* __restrict__ xpc, const int* __restrict__ mask,
        const int* __restrict__ ridx, float* __restrict__ gseq, float* __restrict__ hseq) {
    int b = blockIdx.x & 63;
    int gru = blockIdx.x >> 6;
    const float* rec  = gru ? brec : arec;
    const float* bias = gru ? bbias : abias;
    float* seq = gru ? hseq : gseq;
    int t = threadIdx.x;
    int c4 = t % 96;                       // column group (4 cols each)
    int kc = t / 96;                       // k-chunk 0..7
    int j4 = c4 * 4;
    int krow0 = kc * 16;
    LOADW(0)  LOADW(1)  LOADW(2)  LOADW(3)
    LOADW(4)  LOADW(5)  LOADW(6)  LOADW(7)
    LOADW(8)  LOADW(9)  LOADW(10) LOADW(11)
    LOADW(12) LOADW(13) LOADW(14) LOADW(15)
    __shared__ __attribute__((aligned(16))) float h_lds[DD];
    __shared__ __attribute__((aligned(16))) float part[8 * N3];   // [kc][col]
    __shared__ int smask[TT];
    __shared__ int sridx[TT];
    if (t < TT) { smask[t] = mask[b * TT + t]; sridx[t] = ridx[b * TT + t]; }
    if (t < DD) h_lds[t] = 0.f;
    // gate-thread constants (t < 128): recurrent bias row + input bias row
    float bz_r = 0.f, br_r = 0.f, bh_r = 0.f, bz_i = 0.f, br_i = 0.f, bh_i = 0.f;
    if (t < DD) {
        bz_r = bias[N3 + t];  br_r = bias[N3 + DD + t];  bh_r = bias[N3 + 2 * DD + t];
        bz_i = bias[t];       br_i = bias[DD + t];       bh_i = bias[2 * DD + t];
    }
    float hreg = 0.f;
    __syncthreads();
    const float* xpb = xpc + (size_t)b * TT * NN + gru * N3;
    for (int step = 0; step < TT; ++step) {
        int m = smask[step];               // uniform
        if (!m) {                          // carry-through fast path (no barriers)
            if (t < DD) seq[(size_t)(b * TT + step) * DD + t] = hreg;
            continue;
        }
        float xz = 0.f, xr = 0.f, xh = 0.f;
        if (t < DD) {                      // prefetch input projection (overlaps dot)
            int row = sridx[step];
            if (row >= 0) {
                const float* xrow = xpb + (size_t)row * NN;
                xz = xrow[t]; xr = xrow[DD + t]; xh = xrow[2 * DD + t];
            } else {                       // rx row is zero -> xp = input bias
                xz = bz_i; xr = br_i; xh = bh_i;
            }
        }
        float4 acc = {0.f, 0.f, 0.f, 0.f};
        DOTQ(0, 0, 1, 2, 3)
        DOTQ(1, 4, 5, 6, 7)
        DOTQ(2, 8, 9, 10, 11)
        DOTQ(3, 12, 13, 14, 15)
        *reinterpret_cast<float4*>(&part[kc * N3 + j4]) = acc;
        __syncthreads();
        if (t < DD) {
            float hz = bz_r, hr = br_r, hh = bh_r;
            #pragma unroll
            for (int g = 0; g < 8; ++g) {
                hz += part[g * N3 + t];
                hr += part[g * N3 + DD + t];
                hh += part[g * N3 + 2 * DD + t];
            }
            float z = fast_sigmoid(xz + hz);
            float r = fast_sigmoid(xr + hr);
            float hc = fast_tanh(xh + r * hh);
            float hnew = z * hreg + (1.f - z) * hc;
            hreg = hnew;
            h_lds[t] = hnew;
            seq[(size_t)(b * TT + step) * DD + t] = hnew;
        }
        __syncthreads();
    }
}

// K5: alpha = softmax_t(gseq @ alpha_w + alpha_b)
__global__ __launch_bounds__(128) void k_alpha(const float* __restrict__ gseq,
        const float* __restrict__ alpha_w, const float* __restrict__ alpha_b,
        float* __restrict__ alpha) {
    int b = blockIdx.x, t = threadIdx.x;
    __shared__ float aw[DD];
    aw[t] = alpha_w[t];
    __syncthreads();
    const float* g = gseq + (size_t)(b * TT + t) * DD;
    float acc = 0.f;
    #pragma unroll
    for (int k = 0; k < DD; k += 4) {
        float4 gv = *reinterpret_cast<const float4*>(g + k);
        acc = fmaf(gv.x, aw[k],     acc);
        acc = fmaf(gv.y, aw[k + 1], acc);
        acc = fmaf(gv.z, aw[k + 2], acc);
        acc = fmaf(gv.w, aw[k + 3], acc);
    }
    float logit = acc + alpha_b[0];
    float mx = logit;
    #pragma unroll
    for (int off = 32; off; off >>= 1) mx = fmaxf(mx, __shfl_xor(mx, off));
    __shared__ float redm[2];
    if ((t & 63) == 0) redm[t >> 6] = mx;
    __syncthreads();
    mx = fmaxf(redm[0], redm[1]);
    float e = expf(logit - mx);
    float s = e;
    #pragma unroll
    for (int off = 32; off; off >>= 1) s += __shfl_xor(s, off);
    __shared__ float reds[2];
    if ((t & 63) == 0) reds[t >> 6] = s;
    __syncthreads();
    alpha[b * TT + t] = e / (reds[0] + reds[1]);
}

// K6: cpart[(b,grp)] = sum over 16 t's of alpha * tanh(h @ beta_w + beta_b) * x
__global__ __launch_bounds__(128) void k_beta(const float* __restrict__ hseq,
        const float* __restrict__ x, const float* __restrict__ beta_w,
        const float* __restrict__ beta_b, const float* __restrict__ alpha,
        float* __restrict__ cpart) {
    __shared__ __attribute__((aligned(16))) float bw[DD][DD];   // 64 KB
    __shared__ __attribute__((aligned(16))) float hr[4][DD];
    __shared__ float cred[4][DD];
    int b = blockIdx.x >> 3, grp = blockIdx.x & 7;
    int tid = threadIdx.x;
    for (int i = tid; i < DD * DD / 4; i += 128) {
        float4 v = *reinterpret_cast<const float4*>(beta_w + (size_t)i * 4);
        *reinterpret_cast<float4*>(&bw[0][0] + (size_t)i * 4) = v;
    }
    int trow = tid >> 5, dq = (tid & 31) * 4;
    float bb0 = beta_b[dq], bb1 = beta_b[dq + 1], bb2 = beta_b[dq + 2], bb3 = beta_b[dq + 3];
    float c0 = 0.f, c1 = 0.f, c2 = 0.f, c3 = 0.f;
    for (int tg = 0; tg < 4; ++tg) {
        int t = grp * 16 + tg * 4 + trow;
        size_t rowoff = (size_t)(b * TT + t) * DD;
        float4 hv = *reinterpret_cast<const float4*>(hseq + rowoff + dq);
        __syncthreads();                    // protect previous iteration's hr readers
        *reinterpret_cast<float4*>(&hr[trow][dq]) = hv;
        __syncthreads();
        float a0 = 0.f, a1 = 0.f, a2 = 0.f, a3 = 0.f;
        #pragma unroll 8
        for (int k = 0; k < DD; ++k) {
            float hk = hr[trow][k];
            float4 w = *reinterpret_cast<const float4*>(&bw[k][dq]);
            a0 = fmaf(hk, w.x, a0); a1 = fmaf(hk, w.y, a1);
            a2 = fmaf(hk, w.z, a2); a3 = fmaf(hk, w.w, a3);
        }
        float al = alpha[b * TT + t];
        float4 xv = *reinterpret_cast<const float4*>(x + rowoff + dq);
        c0 = fmaf(al * tanhf(a0 + bb0), xv.x, c0);
        c1 = fmaf(al * tanhf(a1 + bb1), xv.y, c1);
        c2 = fmaf(al * tanhf(a2 + bb2), xv.z, c2);
        c3 = fmaf(al * tanhf(a3 + bb3), xv.w, c3);
    }
    cred[trow][dq] = c0; cred[trow][dq + 1] = c1;
    cred[trow][dq + 2] = c2; cred[trow][dq + 3] = c3;
    __syncthreads();
    if (tid < 32) {
        #pragma unroll
        for (int i = 0; i < 4; ++i) {
            int d = tid * 4 + i;
            float sum = cred[0][d] + cred[1][d] + cred[2][d] + cred[3][d];
            cpart[(size_t)(b * 8 + grp) * DD + d] = sum;
        }
    }
}

// K7: out[b] = (sum of 8 cpart slices) @ cls_w + cls_b
__global__ __launch_bounds__(256) void k_out(const float* __restrict__ cpart,
        const float* __restrict__ cls_w, const float* __restrict__ cls_b,
        float* __restrict__ out) {
    __shared__ float cl[DD];
    int b = blockIdx.x, tid = threadIdx.x;
    if (tid < DD) {
        float s = 0.f;
        #pragma unroll
        for (int p = 0; p < 8; ++p) s += cpart[(size_t)(b * 8 + p) * DD + tid];
        cl[tid] = s;
    }
    __syncthreads();
    #pragma unroll
    for (int rep = 0; rep < 2; ++rep) {
        int o = tid + rep * 256;
        float acc = cls_b[o];
        #pragma unroll 8
        for (int k = 0; k < DD; ++k)
            acc = fmaf(cl[k], cls_w[(size_t)k * OO + o], acc);
        out[(size_t)b * OO + o] = acc;
    }
}

extern "C" void kernel_launch(void* const* d_in, const int* in_sizes, int n_in,
                              void* d_out, int out_size, void* d_ws, size_t ws_size,
                              hipStream_t stream) {
    const int*   codes   = (const int*)d_in[0];
    const float* emb     = (const float*)d_in[1];
    const float* akern   = (const float*)d_in[2];
    const float* arec    = (const float*)d_in[3];
    const float* abias   = (const float*)d_in[4];
    const float* bkern   = (const float*)d_in[5];
    const float* brec    = (const float*)d_in[6];
    const float* bbias   = (const float*)d_in[7];
    const float* alpha_w = (const float*)d_in[8];
    const float* alpha_b = (const float*)d_in[9];
    const float* beta_w  = (const float*)d_in[10];
    const float* beta_b  = (const float*)d_in[11];
    const float* cls_w   = (const float*)d_in[12];
    const float* cls_b   = (const float*)d_in[13];
    float* ws   = (float*)d_ws;
    float* x    = ws + OFF_X;
    float* xpc  = ws + OFF_XPC;
    float* gseq = ws + OFF_GSEQ;
    float* hseq = ws + OFF_HSEQ;
    int*   ints = (int*)(ws + OFF_INTS);
    int* mask    = ints;
    int* ridx    = ints + 8192;
    int* lengths = ints + 16384;
    float* alpha = ws + OFF_ALPHA;
    float* cpart = ws + OFF_CPART;
    float* out   = (float*)d_out;

    k_gather<<<BATCH * TT, 128, 0, stream>>>(codes, emb, x, mask);
    k_len<<<BATCH, 128, 0, stream>>>(mask, lengths, ridx);
    dim3 g3(128, 12);
    k_xp<<<g3, 256, 0, stream>>>(x, akern, bkern, abias, bbias, xpc);
    k_gru<<<128, 768, 0, stream>>>(arec, abias, brec, bbias, xpc, mask, ridx, gseq, hseq);
    k_alpha<<<BATCH, 128, 0, stream>>>(gseq, alpha_w, alpha_b, alpha);
    k_beta<<<BATCH * 8, 128, 0, stream>>>(hseq, x, beta_w, beta_b, alpha, cpart);
    k_out<<<BATCH, 256, 0, stream>>>(cpart, cls_w, cls_b, out);
}